// Round 7
// baseline (1593.709 us; speedup 1.0000x reference)
//
#include <hip/hip_runtime.h>
#include <hip/hip_bf16.h>
#include <math.h>

// B=64, S=128, V=50257, E=1024, H=1024, G=3H=3072
#define GRU_B 64
#define GRU_S 128
#define GRU_E 1024
#define GRU_H 1024
#define GRU_G 3072

typedef _Float16 half8 __attribute__((ext_vector_type(8)));
typedef _Float16 half4v __attribute__((ext_vector_type(4)));
typedef float floatx4 __attribute__((ext_vector_type(4)));

__device__ __forceinline__ half8 cvt_h8(float4 a, float4 b) {
    half8 r;
    r[0] = (_Float16)a.x; r[1] = (_Float16)a.y;
    r[2] = (_Float16)a.z; r[3] = (_Float16)a.w;
    r[4] = (_Float16)b.x; r[5] = (_Float16)b.y;
    r[6] = (_Float16)b.z; r[7] = (_Float16)b.w;
    return r;
}

// ---------------------------------------------------------------------------
// Phase 1 (unchanged, proven): x_proj = emb[tok] @ w_ih^T + b_ih, fp16 MFMA.
// ---------------------------------------------------------------------------
__global__ __launch_bounds__(256) void xproj_mfma(
    const int* __restrict__ tokens,     // [B][S]
    const float* __restrict__ emb,      // [V][E]
    const float* __restrict__ w_ih,     // [G][E]
    const float* __restrict__ b_ih,     // [G]
    float* __restrict__ xproj)          // [M][G], m = s*64+b
{
    __shared__ __attribute__((aligned(16))) _Float16 Al[128 * 32];
    __shared__ __attribute__((aligned(16))) _Float16 Bl[128 * 32];
    __shared__ int toks[128];

    const int t  = threadIdx.x;
    const int m0 = blockIdx.x * 128;
    const int n0 = blockIdx.y * 128;

    if (t < 128) {
        int m = m0 + t;
        toks[t] = tokens[(m & 63) * GRU_S + (m >> 6)];   // tokens[b][s]
    }

    const int wid = t >> 6;
    const int l   = t & 63;
    const int wm  = (wid >> 1) * 64;
    const int wn  = (wid & 1) * 64;

    const int sr   = t >> 1;
    const int skw  = (sr >> 1) & 3;
    const int gb   = (t & 1) * 2;

    const int fr   = l & 15;
    const int ag   = l >> 4;
    const int skey = (fr >> 1) & 3;
    const int gfr  = (ag ^ skey) * 16;

    char* ab = reinterpret_cast<char*>(Al);
    char* bb = reinterpret_cast<char*>(Bl);

    floatx4 acc[4][4];
#pragma unroll
    for (int i = 0; i < 4; ++i)
#pragma unroll
        for (int j = 0; j < 4; ++j)
            acc[i][j] = (floatx4){0.f, 0.f, 0.f, 0.f};

    for (int k0 = 0; k0 < GRU_E; k0 += 32) {
        __syncthreads();
        {
            const float4* asrc = reinterpret_cast<const float4*>(
                emb + (size_t)toks[sr] * GRU_E + k0 + (t & 1) * 16);
            const float4* bsrc = reinterpret_cast<const float4*>(
                w_ih + (size_t)(n0 + sr) * GRU_E + k0 + (t & 1) * 16);
            float4 a0 = asrc[0], a1 = asrc[1], a2 = asrc[2], a3 = asrc[3];
            float4 b0 = bsrc[0], b1 = bsrc[1], b2 = bsrc[2], b3 = bsrc[3];
            *reinterpret_cast<half8*>(ab + sr * 64 + ((gb + 0) ^ skw) * 16) = cvt_h8(a0, a1);
            *reinterpret_cast<half8*>(ab + sr * 64 + ((gb + 1) ^ skw) * 16) = cvt_h8(a2, a3);
            *reinterpret_cast<half8*>(bb + sr * 64 + ((gb + 0) ^ skw) * 16) = cvt_h8(b0, b1);
            *reinterpret_cast<half8*>(bb + sr * 64 + ((gb + 1) ^ skw) * 16) = cvt_h8(b2, b3);
        }
        __syncthreads();

        half8 a4[4], b4[4];
#pragma unroll
        for (int mi = 0; mi < 4; ++mi)
            a4[mi] = *reinterpret_cast<const half8*>(ab + (wm + mi * 16 + fr) * 64 + gfr);
#pragma unroll
        for (int ni = 0; ni < 4; ++ni)
            b4[ni] = *reinterpret_cast<const half8*>(bb + (wn + ni * 16 + fr) * 64 + gfr);
#pragma unroll
        for (int mi = 0; mi < 4; ++mi)
#pragma unroll
            for (int ni = 0; ni < 4; ++ni)
                acc[mi][ni] = __builtin_amdgcn_mfma_f32_16x16x32_f16(
                    a4[mi], b4[ni], acc[mi][ni], 0, 0, 0);
    }

    const int cr = (l >> 4) * 4;
    const int cc = l & 15;
#pragma unroll
    for (int ni = 0; ni < 4; ++ni) {
        int n = n0 + wn + ni * 16 + cc;
        float bias = b_ih[n];
#pragma unroll
        for (int mi = 0; mi < 4; ++mi) {
#pragma unroll
            for (int q = 0; q < 4; ++q) {
                int m = m0 + wm + mi * 16 + cr + q;
                xproj[(size_t)m * GRU_G + n] = acc[mi][ni][q] + bias;
            }
        }
    }
}

// ---------------------------------------------------------------------------
// Phase 2: persistent GRU, R4-proven fence protocol with re-scheduled fences.
//   publish (t0): [syncthreads already drained all waves' stores to L2]
//                 fence(release,agent)  -> wbl2 + waits   (R4-proven)
//                 flags[jb] = step      (relaxed agent store)
//   speculative acquire (ALL waves):  fence(acquire,agent) -> inv L1/L2,
//                 executed BEFORE the poll; nothing re-caches h lines
//                 between inv and the post-poll loads.
//   poll (ALL waves): lane l watches flags[l]; exit when __all(f >= tgt).
//   h loads: plain cached loads (fresh, caches were invalidated). R4-proven.
// ---------------------------------------------------------------------------
__global__ __launch_bounds__(256) void gru_persist(
    const float* __restrict__ xproj,    // [S][B][G]
    const float* __restrict__ w_hh,     // [G][H]
    const float* __restrict__ b_hh,     // [G]
    _Float16* __restrict__ hb,          // 2 x [64][1024] fp16
    float* __restrict__ out,            // [64][1024]
    int* __restrict__ flags)            // [64], zeroed by host
{
    __shared__ __attribute__((aligned(16))) _Float16 wlds[48 * 1024];  // 96 KB

    const int t   = threadIdx.x;
    const int jb  = blockIdx.x;         // 0..63
    const int l   = t & 63;
    const int wid = t >> 6;
    const int m0  = wid * 16;

    // ---- stage W: 48 rows (gate*16+jloc), fp32 -> fp16, swizzled ----
    {
        char* wbp = reinterpret_cast<char*>(wlds);
        for (int r = 0; r < 48; ++r) {
            int grow = (r >> 4) * GRU_H + jb * 16 + (r & 15);
            float4 v = reinterpret_cast<const float4*>(
                w_hh + (size_t)grow * GRU_H)[t];
            half4v hv;
            hv.x = (_Float16)v.x; hv.y = (_Float16)v.y;
            hv.z = (_Float16)v.z; hv.w = (_Float16)v.w;
            int g = (t >> 1) ^ (r & 7);
            *reinterpret_cast<half4v*>(wbp + r * 2048 + g * 16 + (t & 1) * 8) = hv;
        }
    }

    // ---- zero broadcast buffer 0 (h(0)=0), plain stores ----
    {
        unsigned int* z = reinterpret_cast<unsigned int*>(hb);
        int i0 = jb * 256 + t;
        z[i0] = 0u;
        z[i0 + 16384] = 0u;
    }

    // ---- per-thread constants ----
    const int jl   = l & 15;
    const int qrow = (l >> 4) * 4;
    const int j    = jb * 16 + jl;
    const float bhr = b_hh[j];
    const float bhz = b_hh[GRU_H + j];
    const float bhn = b_hh[2 * GRU_H + j];

    const int arow  = m0 + (l & 15);         // A-frag h row
    const int akoff = (l >> 4) * 8;          // A-frag k offset (elements)
    const int sk    = jl & 7;
    const char* wb  = reinterpret_cast<const char*>(wlds);
    const int bbase0 = (0 * 16 + jl) * 2048;
    const int bbase1 = (1 * 16 + jl) * 2048;
    const int bbase2 = (2 * 16 + jl) * 2048;

    float hp[4] = {0.f, 0.f, 0.f, 0.f};
    float xr[4], xz[4], xnn[4];

    // ---- initial publish: h zeroed -> flag = 1; speculative acquire; prefetch
    __syncthreads();                                  // all stores drained to L2
    if (t == 0) {
        __builtin_amdgcn_fence(__ATOMIC_RELEASE, "agent");   // wbl2 + waits
        __hip_atomic_store(flags + jb, 1, __ATOMIC_RELAXED,
                           __HIP_MEMORY_SCOPE_AGENT);
    }
    __builtin_amdgcn_fence(__ATOMIC_ACQUIRE, "agent");       // inv (pre-poll)
#pragma unroll
    for (int q = 0; q < 4; ++q) {
        const float* row = xproj + (size_t)(m0 + qrow + q) * GRU_G;
        xr[q]  = row[j];
        xz[q]  = row[GRU_H + j];
        xnn[q] = row[2 * GRU_H + j];
    }

    for (int s = 0; s < GRU_S; ++s) {
        // ---- poll: every wave watches all 64 flags (lane l <-> flags[l]) ----
        {
            const int tgt = s + 1;
            while (true) {
                int f = __hip_atomic_load(flags + l, __ATOMIC_RELAXED,
                                          __HIP_MEMORY_SCOPE_AGENT);
                if (__all(f >= tgt)) break;
            }
        }
        asm volatile("" ::: "memory");   // pin h loads after the poll

        const _Float16* hc = hb + (size_t)(s & 1) * (GRU_B * GRU_H);
        _Float16*       hn = hb + (size_t)((s + 1) & 1) * (GRU_B * GRU_H);

        floatx4 acc0 = {0.f, 0.f, 0.f, 0.f};
        floatx4 acc1 = {0.f, 0.f, 0.f, 0.f};
        floatx4 acc2 = {0.f, 0.f, 0.f, 0.f};

        const _Float16* aptr = hc + (size_t)arow * GRU_H + akoff;

#pragma unroll 4
        for (int k0 = 0; k0 < GRU_H; k0 += 32) {
            half8 a = *reinterpret_cast<const half8*>(aptr + k0);
            int g = ((k0 >> 3) + (l >> 4)) ^ sk;
            half8 b0 = *reinterpret_cast<const half8*>(wb + bbase0 + g * 16);
            half8 b1 = *reinterpret_cast<const half8*>(wb + bbase1 + g * 16);
            half8 b2 = *reinterpret_cast<const half8*>(wb + bbase2 + g * 16);
            acc0 = __builtin_amdgcn_mfma_f32_16x16x32_f16(a, b0, acc0, 0, 0, 0);
            acc1 = __builtin_amdgcn_mfma_f32_16x16x32_f16(a, b1, acc1, 0, 0, 0);
            acc2 = __builtin_amdgcn_mfma_f32_16x16x32_f16(a, b2, acc2, 0, 0, 0);
        }

        const bool last = (s == GRU_S - 1);

        // ---- fused gate epilogue; plain h stores ----
#pragma unroll
        for (int q = 0; q < 4; ++q) {
            float r  = 1.f / (1.f + __expf(-(xr[q] + acc0[q] + bhr)));
            float zg = 1.f / (1.f + __expf(-(xz[q] + acc1[q] + bhz)));
            float pre = xnn[q] + r * (acc2[q] + bhn);
            pre = fminf(fmaxf(pre, -15.f), 15.f);
            float e2 = __expf(2.f * pre);
            float ng = (e2 - 1.f) / (e2 + 1.f);
            float h  = (1.f - zg) * ng + zg * hp[q];
            hp[q] = h;
            if (!last)
                hn[(size_t)(m0 + qrow + q) * GRU_H + j] = (_Float16)h;
        }

        if (!last) {
            // publish step s+2, speculative acquire, prefetch xproj[s+1]
            __syncthreads();                           // all h stores in L2
            if (t == 0) {
                __builtin_amdgcn_fence(__ATOMIC_RELEASE, "agent");
                __hip_atomic_store(flags + jb, s + 2, __ATOMIC_RELAXED,
                                   __HIP_MEMORY_SCOPE_AGENT);
            }
            __builtin_amdgcn_fence(__ATOMIC_ACQUIRE, "agent");  // inv, pre-poll
            const float* xpS = xproj + (size_t)(s + 1) * (GRU_B * GRU_G);
#pragma unroll
            for (int q = 0; q < 4; ++q) {
                const float* row = xpS + (size_t)(m0 + qrow + q) * GRU_G;
                xr[q]  = row[j];
                xz[q]  = row[GRU_H + j];
                xnn[q] = row[2 * GRU_H + j];
            }
        }
    }

    // final hidden state -> output (fp32, plain stores)
#pragma unroll
    for (int q = 0; q < 4; ++q)
        out[(size_t)(m0 + qrow + q) * GRU_H + j] = hp[q];
}

// ---------------------------------------------------------------------------
// Launch
// ---------------------------------------------------------------------------
extern "C" void kernel_launch(void* const* d_in, const int* in_sizes, int n_in,
                              void* d_out, int out_size, void* d_ws, size_t ws_size,
                              hipStream_t stream) {
    const int*   tokens = (const int*)  d_in[0];
    const float* emb    = (const float*)d_in[1];
    const float* w_ih   = (const float*)d_in[2];
    const float* w_hh   = (const float*)d_in[3];
    const float* b_ih   = (const float*)d_in[4];
    const float* b_hh   = (const float*)d_in[5];
    float* out = (float*)d_out;

    float*    xproj = (float*)d_ws;                                       // 96 MB
    _Float16* hb    = (_Float16*)(xproj + (size_t)GRU_S * GRU_B * GRU_G); // 256 KB
    int*      flags = (int*)(hb + 2 * (size_t)GRU_B * GRU_H);             // 64 ints

    hipMemsetAsync(flags, 0, 64 * sizeof(int), stream);

    {
        dim3 grid(GRU_B * GRU_S / 128, GRU_G / 128);   // 64 x 24
        xproj_mfma<<<grid, 256, 0, stream>>>(tokens, emb, w_ih, b_ih, xproj);
    }

    {
        const float* xp_a = xproj;
        const float* whh_a = w_hh;
        const float* bhh_a = b_hh;
        _Float16* hb_a = hb;
        float* out_a = out;
        int* flags_a = flags;
        void* args[] = { (void*)&xp_a, (void*)&whh_a, (void*)&bhh_a,
                         (void*)&hb_a, (void*)&out_a, (void*)&flags_a };
        hipLaunchCooperativeKernel((void*)gru_persist, dim3(64), dim3(256),
                                   args, 0, stream);
    }
}

// Round 8
// 1519.038 us; speedup vs baseline: 1.0492x; 1.0492x over previous
//
#include <hip/hip_runtime.h>
#include <hip/hip_bf16.h>
#include <math.h>

// B=64, S=128, V=50257, E=1024, H=1024, G=3H=3072
#define GRU_B 64
#define GRU_S 128
#define GRU_E 1024
#define GRU_H 1024
#define GRU_G 3072

typedef _Float16 half8 __attribute__((ext_vector_type(8)));
typedef _Float16 half4v __attribute__((ext_vector_type(4)));
typedef float floatx4 __attribute__((ext_vector_type(4)));
typedef unsigned long long ull2 __attribute__((ext_vector_type(2)));

__device__ __forceinline__ half8 cvt_h8(float4 a, float4 b) {
    half8 r;
    r[0] = (_Float16)a.x; r[1] = (_Float16)a.y;
    r[2] = (_Float16)a.z; r[3] = (_Float16)a.w;
    r[4] = (_Float16)b.x; r[5] = (_Float16)b.y;
    r[6] = (_Float16)b.z; r[7] = (_Float16)b.w;
    return r;
}

// ---------------------------------------------------------------------------
// Phase 1 (unchanged, proven): x_proj = emb[tok] @ w_ih^T + b_ih, fp16 MFMA.
// ---------------------------------------------------------------------------
__global__ __launch_bounds__(256) void xproj_mfma(
    const int* __restrict__ tokens,     // [B][S]
    const float* __restrict__ emb,      // [V][E]
    const float* __restrict__ w_ih,     // [G][E]
    const float* __restrict__ b_ih,     // [G]
    float* __restrict__ xproj)          // [M][G], m = s*64+b
{
    __shared__ __attribute__((aligned(16))) _Float16 Al[128 * 32];
    __shared__ __attribute__((aligned(16))) _Float16 Bl[128 * 32];
    __shared__ int toks[128];

    const int t  = threadIdx.x;
    const int m0 = blockIdx.x * 128;
    const int n0 = blockIdx.y * 128;

    if (t < 128) {
        int m = m0 + t;
        toks[t] = tokens[(m & 63) * GRU_S + (m >> 6)];   // tokens[b][s]
    }

    const int wid = t >> 6;
    const int l   = t & 63;
    const int wm  = (wid >> 1) * 64;
    const int wn  = (wid & 1) * 64;

    const int sr   = t >> 1;
    const int skw  = (sr >> 1) & 3;
    const int gb   = (t & 1) * 2;

    const int fr   = l & 15;
    const int ag   = l >> 4;
    const int skey = (fr >> 1) & 3;
    const int gfr  = (ag ^ skey) * 16;

    char* ab = reinterpret_cast<char*>(Al);
    char* bb = reinterpret_cast<char*>(Bl);

    floatx4 acc[4][4];
#pragma unroll
    for (int i = 0; i < 4; ++i)
#pragma unroll
        for (int j = 0; j < 4; ++j)
            acc[i][j] = (floatx4){0.f, 0.f, 0.f, 0.f};

    for (int k0 = 0; k0 < GRU_E; k0 += 32) {
        __syncthreads();
        {
            const float4* asrc = reinterpret_cast<const float4*>(
                emb + (size_t)toks[sr] * GRU_E + k0 + (t & 1) * 16);
            const float4* bsrc = reinterpret_cast<const float4*>(
                w_ih + (size_t)(n0 + sr) * GRU_E + k0 + (t & 1) * 16);
            float4 a0 = asrc[0], a1 = asrc[1], a2 = asrc[2], a3 = asrc[3];
            float4 b0 = bsrc[0], b1 = bsrc[1], b2 = bsrc[2], b3 = bsrc[3];
            *reinterpret_cast<half8*>(ab + sr * 64 + ((gb + 0) ^ skw) * 16) = cvt_h8(a0, a1);
            *reinterpret_cast<half8*>(ab + sr * 64 + ((gb + 1) ^ skw) * 16) = cvt_h8(a2, a3);
            *reinterpret_cast<half8*>(bb + sr * 64 + ((gb + 0) ^ skw) * 16) = cvt_h8(b0, b1);
            *reinterpret_cast<half8*>(bb + sr * 64 + ((gb + 1) ^ skw) * 16) = cvt_h8(b2, b3);
        }
        __syncthreads();

        half8 a4[4], b4[4];
#pragma unroll
        for (int mi = 0; mi < 4; ++mi)
            a4[mi] = *reinterpret_cast<const half8*>(ab + (wm + mi * 16 + fr) * 64 + gfr);
#pragma unroll
        for (int ni = 0; ni < 4; ++ni)
            b4[ni] = *reinterpret_cast<const half8*>(bb + (wn + ni * 16 + fr) * 64 + gfr);
#pragma unroll
        for (int mi = 0; mi < 4; ++mi)
#pragma unroll
            for (int ni = 0; ni < 4; ++ni)
                acc[mi][ni] = __builtin_amdgcn_mfma_f32_16x16x32_f16(
                    a4[mi], b4[ni], acc[mi][ni], 0, 0, 0);
    }

    const int cr = (l >> 4) * 4;
    const int cc = l & 15;
#pragma unroll
    for (int ni = 0; ni < 4; ++ni) {
        int n = n0 + wn + ni * 16 + cc;
        float bias = b_ih[n];
#pragma unroll
        for (int mi = 0; mi < 4; ++mi) {
#pragma unroll
            for (int q = 0; q < 4; ++q) {
                int m = m0 + wm + mi * 16 + cr + q;
                xproj[(size_t)m * GRU_G + n] = acc[mi][ni][q] + bias;
            }
        }
    }
}

// ---------------------------------------------------------------------------
// Phase 2: persistent GRU, IF-direct protocol (no wbl2, no inv).
//   h writes: 4-lane packed returnless global_atomic_swap_x2 (agent scope)
//             -> executes AT the Infinity Fabric coherence point; vmcnt-acked
//             there, so __syncthreads guarantees global visibility.
//   publish:  t0 relaxed agent flag store (visibility pair proven R4/R7).
//   poll:     wave0, lane l <-> flags[l], __all, s_sleep(1).
//   h reads:  SYSTEM-scope (sc0 sc1) relaxed 8B atomic loads = bypass stale
//             L1/L2, read IF. Pinned after the poll by sched_barrier + asm
//             memory clobber (the R5/R6 suspect was compile-time hoisting).
// ---------------------------------------------------------------------------
__global__ __launch_bounds__(256) void gru_persist(
    const float* __restrict__ xproj,    // [S][B][G]
    const float* __restrict__ w_hh,     // [G][H]
    const float* __restrict__ b_hh,     // [G]
    _Float16* __restrict__ hb,          // 2 x [64][1024] fp16
    float* __restrict__ out,            // [64][1024]
    int* __restrict__ flags)            // [64], zeroed by host
{
    __shared__ __attribute__((aligned(16))) _Float16 wlds[48 * 1024];  // 96 KB

    const int t   = threadIdx.x;
    const int jb  = blockIdx.x;         // 0..63
    const int l   = t & 63;
    const int wid = t >> 6;
    const int m0  = wid * 16;

    // ---- stage W: 48 rows (gate*16+jloc), fp32 -> fp16, swizzled ----
    {
        char* wbp = reinterpret_cast<char*>(wlds);
        for (int r = 0; r < 48; ++r) {
            int grow = (r >> 4) * GRU_H + jb * 16 + (r & 15);
            float4 v = reinterpret_cast<const float4*>(
                w_hh + (size_t)grow * GRU_H)[t];
            half4v hv;
            hv.x = (_Float16)v.x; hv.y = (_Float16)v.y;
            hv.z = (_Float16)v.z; hv.w = (_Float16)v.w;
            int g = (t >> 1) ^ (r & 7);
            *reinterpret_cast<half4v*>(wbp + r * 2048 + g * 16 + (t & 1) * 8) = hv;
        }
    }

    // ---- zero broadcast buffer 0 (h(0)=0) via IF-direct swaps ----
    {
        unsigned long long* z = reinterpret_cast<unsigned long long*>(hb);
        int i0 = jb * 256 + t;          // 16384 ull = buffer 0 (128 KB)
        (void)__hip_atomic_exchange(z + i0, 0ULL, __ATOMIC_RELAXED,
                                    __HIP_MEMORY_SCOPE_AGENT);
    }

    // ---- per-thread constants ----
    const int jl   = l & 15;
    const int qrow = (l >> 4) * 4;
    const int j    = jb * 16 + jl;
    const float bhr = b_hh[j];
    const float bhz = b_hh[GRU_H + j];
    const float bhn = b_hh[2 * GRU_H + j];

    const int arow   = m0 + (l & 15);        // A-frag h row
    const int aoff64 = (l >> 4) * 2;         // A-frag k offset in ull units
    const int sk     = jl & 7;
    const char* wb   = reinterpret_cast<const char*>(wlds);
    const int bbase0 = (0 * 16 + jl) * 2048;
    const int bbase1 = (1 * 16 + jl) * 2048;
    const int bbase2 = (2 * 16 + jl) * 2048;

    // packed h-write constants: 4-lane group leader stores one ull per q-row
    const int colq   = (jb * 16 + jl) >> 2;  // ull column within a 256-ull row
    const bool leader = ((l & 3) == 0);

    float hp[4] = {0.f, 0.f, 0.f, 0.f};
    float xr[4], xz[4], xnn[4];

    // ---- initial publish: zero-swaps acked at IF -> flag = 1 ----
    __syncthreads();                         // vmcnt(0): swaps complete at IF
    if (t == 0)
        __hip_atomic_store(flags + jb, 1, __ATOMIC_RELAXED,
                           __HIP_MEMORY_SCOPE_AGENT);
    asm volatile("" ::: "memory");

    // prefetch x_proj for step 0 (plain cached loads; L2 stays warm now)
#pragma unroll
    for (int q = 0; q < 4; ++q) {
        const float* row = xproj + (size_t)(m0 + qrow + q) * GRU_G;
        xr[q]  = row[j];
        xz[q]  = row[GRU_H + j];
        xnn[q] = row[2 * GRU_H + j];
    }

    for (int s = 0; s < GRU_S; ++s) {
        // ---- wait: all blocks published phase s+1 (wave0 only, calm poll) ----
        if (wid == 0) {
            const int tgt = s + 1;
            while (true) {
                int f = __hip_atomic_load(flags + l, __ATOMIC_RELAXED,
                                          __HIP_MEMORY_SCOPE_AGENT);
                if (__all(f >= tgt)) break;
                __builtin_amdgcn_s_sleep(1);
            }
        }
        __syncthreads();
        __builtin_amdgcn_sched_barrier(0);
        asm volatile("" ::: "memory");   // pin h loads after the poll

        const _Float16* hc = hb + (size_t)(s & 1) * (GRU_B * GRU_H);
        _Float16*       hn = hb + (size_t)((s + 1) & 1) * (GRU_B * GRU_H);

        const unsigned long long* abase =
            reinterpret_cast<const unsigned long long*>(hc + (size_t)arow * GRU_H)
            + aoff64;

        floatx4 acc0 = {0.f, 0.f, 0.f, 0.f};
        floatx4 acc1 = {0.f, 0.f, 0.f, 0.f};
        floatx4 acc2 = {0.f, 0.f, 0.f, 0.f};

#pragma unroll 8
        for (int kc = 0; kc < 32; ++kc) {
            // bypass loads: read h at the IF (fresh, swap-written)
            unsigned long long a0 = __hip_atomic_load(abase + kc * 8,
                __ATOMIC_RELAXED, __HIP_MEMORY_SCOPE_SYSTEM);
            unsigned long long a1 = __hip_atomic_load(abase + kc * 8 + 1,
                __ATOMIC_RELAXED, __HIP_MEMORY_SCOPE_SYSTEM);
            ull2 tmp; tmp.x = a0; tmp.y = a1;
            half8 a = __builtin_bit_cast(half8, tmp);
            int g = (kc * 4 + (l >> 4)) ^ sk;
            half8 b0 = *reinterpret_cast<const half8*>(wb + bbase0 + g * 16);
            half8 b1 = *reinterpret_cast<const half8*>(wb + bbase1 + g * 16);
            half8 b2 = *reinterpret_cast<const half8*>(wb + bbase2 + g * 16);
            acc0 = __builtin_amdgcn_mfma_f32_16x16x32_f16(a, b0, acc0, 0, 0, 0);
            acc1 = __builtin_amdgcn_mfma_f32_16x16x32_f16(a, b1, acc1, 0, 0, 0);
            acc2 = __builtin_amdgcn_mfma_f32_16x16x32_f16(a, b2, acc2, 0, 0, 0);
        }

        const bool last = (s == GRU_S - 1);

        // ---- fused gate epilogue ----
        unsigned int dw[4];
#pragma unroll
        for (int q = 0; q < 4; ++q) {
            float r  = 1.f / (1.f + __expf(-(xr[q] + acc0[q] + bhr)));
            float zg = 1.f / (1.f + __expf(-(xz[q] + acc1[q] + bhz)));
            float pre = xnn[q] + r * (acc2[q] + bhn);
            pre = fminf(fmaxf(pre, -15.f), 15.f);
            float e2 = __expf(2.f * pre);
            float ng = (e2 - 1.f) / (e2 + 1.f);
            float h  = (1.f - zg) * ng + zg * hp[q];
            hp[q] = h;
            // pair-pack (j, j+1) into a dword on even lanes
            unsigned int hu = (unsigned int)__builtin_bit_cast(
                unsigned short, (_Float16)h);
            unsigned int ot = (unsigned int)__shfl_xor((int)hu, 1);
            dw[q] = hu | (ot << 16);
        }

        if (!last) {
            // quad-pack (j..j+3) into a qword on 4-lane leaders, swap to IF
            unsigned long long* hn64 = reinterpret_cast<unsigned long long*>(hn);
#pragma unroll
            for (int q = 0; q < 4; ++q) {
                unsigned int hi = (unsigned int)__shfl_xor((int)dw[q], 2);
                if (leader) {
                    unsigned long long qw =
                        (unsigned long long)dw[q] |
                        ((unsigned long long)hi << 32);
                    (void)__hip_atomic_exchange(
                        hn64 + (size_t)(m0 + qrow + q) * 256 + colq, qw,
                        __ATOMIC_RELAXED, __HIP_MEMORY_SCOPE_AGENT);
                }
            }

            __syncthreads();             // vmcnt(0): swaps complete at IF
            if (t == 0)
                __hip_atomic_store(flags + jb, s + 2, __ATOMIC_RELAXED,
                                   __HIP_MEMORY_SCOPE_AGENT);
            asm volatile("" ::: "memory");

            // prefetch x_proj for s+1 (plain cached; flies during next poll)
            const float* xpS = xproj + (size_t)(s + 1) * (GRU_B * GRU_G);
#pragma unroll
            for (int q = 0; q < 4; ++q) {
                const float* row = xpS + (size_t)(m0 + qrow + q) * GRU_G;
                xr[q]  = row[j];
                xz[q]  = row[GRU_H + j];
                xnn[q] = row[2 * GRU_H + j];
            }
        }
    }

    // final hidden state -> output (fp32, plain stores)
#pragma unroll
    for (int q = 0; q < 4; ++q)
        out[(size_t)(m0 + qrow + q) * GRU_H + j] = hp[q];
}

// ---------------------------------------------------------------------------
// Launch
// ---------------------------------------------------------------------------
extern "C" void kernel_launch(void* const* d_in, const int* in_sizes, int n_in,
                              void* d_out, int out_size, void* d_ws, size_t ws_size,
                              hipStream_t stream) {
    const int*   tokens = (const int*)  d_in[0];
    const float* emb    = (const float*)d_in[1];
    const float* w_ih   = (const float*)d_in[2];
    const float* w_hh   = (const float*)d_in[3];
    const float* b_ih   = (const float*)d_in[4];
    const float* b_hh   = (const float*)d_in[5];
    float* out = (float*)d_out;

    float*    xproj = (float*)d_ws;                                       // 96 MB
    _Float16* hb    = (_Float16*)(xproj + (size_t)GRU_S * GRU_B * GRU_G); // 256 KB
    int*      flags = (int*)(hb + 2 * (size_t)GRU_B * GRU_H);             // 64 ints

    hipMemsetAsync(flags, 0, 64 * sizeof(int), stream);

    {
        dim3 grid(GRU_B * GRU_S / 128, GRU_G / 128);   // 64 x 24
        xproj_mfma<<<grid, 256, 0, stream>>>(tokens, emb, w_ih, b_ih, xproj);
    }

    {
        const float* xp_a = xproj;
        const float* whh_a = w_hh;
        const float* bhh_a = b_hh;
        _Float16* hb_a = hb;
        float* out_a = out;
        int* flags_a = flags;
        void* args[] = { (void*)&xp_a, (void*)&whh_a, (void*)&bhh_a,
                         (void*)&hb_a, (void*)&out_a, (void*)&flags_a };
        hipLaunchCooperativeKernel((void*)gru_persist, dim3(64), dim3(256),
                                   args, 0, stream);
    }
}